// Round 1
// baseline (37123.727 us; speedup 1.0000x reference)
//
#include <hip/hip_runtime.h>
#include <hip/hip_bf16.h>

// 2-layer GRU (torch gate order r,z,n) + residual, B=16 T=4096 IN=H=512.
// Persistent pipelined kernel: 32 WGs per layer, each owns 16 hidden units.
// Waves 0-2: input-side matvec (x for layer1, y for layer2) gates r/z/n.
// Waves 3-5: hidden-side matvec gates r/z/n. Weights stationary in VGPRs as
// bf16 MFMA B-fragments. h published bf16 via global ring + monotonic flags
// (value = step+1; flags memset to 0 each launch -> re-poison safe).
// Own h slice kept fp32 in LDS so the z*h path never quantizes.

namespace {

constexpr int BATCH = 16;
constexpr int SEQ   = 4096;
constexpr int HD    = 512;   // hidden == input dim
constexpr int NWG_L = 32;    // workgroups per layer
constexpr int SLICE = 16;    // hidden units per WG
constexpr int RING  = 8;     // ring slots per layer
constexpr int BLK   = 6 * 64;

typedef short bf16x8 __attribute__((ext_vector_type(8)));
typedef float f32x4  __attribute__((ext_vector_type(4)));

__device__ __forceinline__ unsigned short f2bf(float f) {
  unsigned u = __float_as_uint(f);
  return (unsigned short)((u + 0x7fffu + ((u >> 16) & 1u)) >> 16);  // RNE
}
__device__ __forceinline__ float bf2f(unsigned short s) {
  return __uint_as_float(((unsigned)s) << 16);
}

__device__ __forceinline__ void wait_ge(const unsigned* f, unsigned tgt) {
  while (__hip_atomic_load(f, __ATOMIC_RELAXED, __HIP_MEMORY_SCOPE_AGENT) < tgt) {}
}

#define MFMA16(a, b, c) __builtin_amdgcn_mfma_f32_16x16x32_bf16((a), (b), (c), 0, 0, 0)

__global__ __launch_bounds__(BLK, 1) void gru2_kernel(
    const float* __restrict__ x,
    const float* __restrict__ Wih1, const float* __restrict__ Whh1,
    const float* __restrict__ bih1, const float* __restrict__ bhh1,
    const float* __restrict__ Wih2, const float* __restrict__ Whh2,
    const float* __restrict__ bih2, const float* __restrict__ bhh2,
    float* __restrict__ out,
    unsigned* flags,            // [2][32], zeroed each launch
    unsigned short* ring)       // [2][RING][BATCH][HD] bf16
{
  const int wg    = blockIdx.x;
  const int layer = wg >> 5;        // 0 or 1
  const int g     = wg & 31;        // slice id within layer
  const int tid   = threadIdx.x;
  const int w     = tid >> 6;       // wave 0..5
  const int lane  = tid & 63;
  const int nidx  = lane & 15;      // A-row (batch) / B-col (unit) / C-col (unit)
  const int kgrp  = lane >> 4;      // 0..3

  __shared__ float gate_buf[6][16][16];  // [wave][batch][unit] fp32 pre-acts
  __shared__ float h_own[16][16];        // own slice of h, fp32 (memory path)

  const float* Wih = layer ? Wih2 : Wih1;
  const float* Whh = layer ? Whh2 : Whh1;
  const float* bih = layer ? bih2 : bih1;
  const float* bhh = layer ? bhh2 : bhh1;

  unsigned* flags1    = flags;       // layer-1 producers (y)
  unsigned* flags2    = flags + 32;  // layer-2 producers
  unsigned* flags_own = layer ? flags2 : flags1;

  const unsigned short* ring1 = ring;                                  // y ring
  unsigned short* ring_own = ring + (size_t)layer * (RING * BATCH * HD);

  if (tid < 256) h_own[tid >> 4][tid & 15] = 0.f;

  // ---- stationary weight fragments: wave w -> (input|hidden) x gate ----
  const int gate = (w < 3) ? w : (w - 3);
  const float* Wmat = (w < 3) ? Wih : Whh;
  // B[k][n] = W[gate*512 + g*16 + n][k]; lane holds col n=nidx, k = kk*32 + kgrp*8 + i
  const float* wrow = Wmat + ((size_t)gate * HD + (size_t)g * SLICE + nidx) * HD + kgrp * 8;
  bf16x8 bfrag[16];
  #pragma unroll
  for (int kk = 0; kk < 16; ++kk) {
    const float* p = wrow + kk * 32;
    bf16x8 f;
    #pragma unroll
    for (int i = 0; i < 8; ++i) f[i] = (short)f2bf(p[i]);
    bfrag[kk] = f;
  }

  float bi_r = 0, bi_z = 0, bi_n = 0, bh_r = 0, bh_z = 0, bh_n = 0;
  if (tid < 256) {
    int u = g * SLICE + (tid & 15);
    bi_r = bih[u]; bi_z = bih[HD + u]; bi_n = bih[2 * HD + u];
    bh_r = bhh[u]; bh_z = bhh[HD + u]; bh_n = bhh[2 * HD + u];
  }
  __syncthreads();

  for (int t = 0; t < SEQ; ++t) {
    f32x4 ac0 = {0.f,0.f,0.f,0.f}, ac1 = {0.f,0.f,0.f,0.f};
    f32x4 ac2 = {0.f,0.f,0.f,0.f}, ac3 = {0.f,0.f,0.f,0.f};

    if (w < 3) {
      // ---------- input-side matvec ----------
      if (layer == 0) {
        // x fp32 [b][t][k], always ready
        const float* px = x + ((size_t)nidx * SEQ + t) * HD + kgrp * 8;
        #pragma unroll
        for (int kk = 0; kk < 16; ++kk) {
          const float* p = px + kk * 32;
          bf16x8 a;
          #pragma unroll
          for (int i = 0; i < 8; ++i) a[i] = (short)f2bf(p[i]);
          if ((kk & 3) == 0)      ac0 = MFMA16(a, bfrag[kk], ac0);
          else if ((kk & 3) == 1) ac1 = MFMA16(a, bfrag[kk], ac1);
          else if ((kk & 3) == 2) ac2 = MFMA16(a, bfrag[kk], ac2);
          else                    ac3 = MFMA16(a, bfrag[kk], ac3);
        }
      } else {
        // y_t bf16 from layer-1 ring; gated on layer-1 flags >= t+1
        if (lane < 32) wait_ge(&flags1[lane], (unsigned)(t + 1));
        __builtin_amdgcn_fence(__ATOMIC_ACQUIRE, "agent");
        const unsigned short* py =
            ring1 + ((size_t)(t & (RING - 1)) * BATCH + nidx) * HD + kgrp * 8;
        #pragma unroll
        for (int kk = 0; kk < 16; ++kk) {
          bf16x8 a = *(const bf16x8*)(py + kk * 32);
          if ((kk & 3) == 0)      ac0 = MFMA16(a, bfrag[kk], ac0);
          else if ((kk & 3) == 1) ac1 = MFMA16(a, bfrag[kk], ac1);
          else if ((kk & 3) == 2) ac2 = MFMA16(a, bfrag[kk], ac2);
          else                    ac3 = MFMA16(a, bfrag[kk], ac3);
        }
      }
    } else {
      // ---------- hidden-side matvec ----------
      if (t > 0) {
        // own-layer h_{t-1}: all 32 producer flags >= t
        if (lane < 32) {
          wait_ge(&flags_own[lane], (unsigned)t);
        } else if (layer == 0 && t >= RING) {
          // back-pressure: don't overwrite y ring slot before layer-2 consumed it
          wait_ge(&flags2[lane - 32], (unsigned)(t - RING + 1));
        }
        __builtin_amdgcn_fence(__ATOMIC_ACQUIRE, "agent");
        const unsigned short* ph =
            ring_own + ((size_t)((t - 1) & (RING - 1)) * BATCH + nidx) * HD + kgrp * 8;
        #pragma unroll
        for (int kk = 0; kk < 16; ++kk) {
          bf16x8 a = *(const bf16x8*)(ph + kk * 32);
          if ((kk & 3) == 0)      ac0 = MFMA16(a, bfrag[kk], ac0);
          else if ((kk & 3) == 1) ac1 = MFMA16(a, bfrag[kk], ac1);
          else if ((kk & 3) == 2) ac2 = MFMA16(a, bfrag[kk], ac2);
          else                    ac3 = MFMA16(a, bfrag[kk], ac3);
        }
      }
      // t == 0: h = 0 -> matvec contributes 0 (biases added in epilogue)
    }

    f32x4 acc = (ac0 + ac1) + (ac2 + ac3);
    // C/D layout: col = lane&15 (unit), row = (lane>>4)*4 + j (batch)
    #pragma unroll
    for (int j = 0; j < 4; ++j) gate_buf[w][kgrp * 4 + j][nidx] = acc[j];
    __syncthreads();

    // ---------- epilogue: gates + state update + publish ----------
    if (tid < 256) {
      const int b = tid >> 4, u = tid & 15;
      float rp = gate_buf[0][b][u] + bi_r + gate_buf[3][b][u] + bh_r;
      float zp = gate_buf[1][b][u] + bi_z + gate_buf[4][b][u] + bh_z;
      float xn = gate_buf[2][b][u] + bi_n;
      float hn = gate_buf[5][b][u] + bh_n;
      float r = 1.f / (1.f + __expf(-rp));
      float z = 1.f / (1.f + __expf(-zp));
      float n = tanhf(xn + r * hn);
      float hp = h_own[b][u];
      float hv = (1.f - z) * n + z * hp;
      h_own[b][u] = hv;
      ring_own[((size_t)(t & (RING - 1)) * BATCH + b) * HD + g * SLICE + u] = f2bf(hv);
      if (layer == 1) {
        float y = bf2f(ring1[((size_t)(t & (RING - 1)) * BATCH + b) * HD + g * SLICE + u]);
        out[((size_t)b * SEQ + t) * HD + g * SLICE + u] = hv + y;
      }
    }
    __syncthreads();  // drains all waves' global stores (vmcnt(0) before barrier)
    if (tid == 0) {
      __builtin_amdgcn_fence(__ATOMIC_RELEASE, "agent");
      __hip_atomic_store(&flags_own[g], (unsigned)(t + 1),
                         __ATOMIC_RELAXED, __HIP_MEMORY_SCOPE_AGENT);
    }
  }
}

}  // namespace

extern "C" void kernel_launch(void* const* d_in, const int* in_sizes, int n_in,
                              void* d_out, int out_size, void* d_ws, size_t ws_size,
                              hipStream_t stream) {
  const float* x    = (const float*)d_in[0];
  const float* Wih1 = (const float*)d_in[1];
  const float* Whh1 = (const float*)d_in[2];
  const float* bih1 = (const float*)d_in[3];
  const float* bhh1 = (const float*)d_in[4];
  const float* Wih2 = (const float*)d_in[5];
  const float* Whh2 = (const float*)d_in[6];
  const float* bih2 = (const float*)d_in[7];
  const float* bhh2 = (const float*)d_in[8];

  unsigned* flags = (unsigned*)d_ws;                                  // 2*32 u32
  unsigned short* ring = (unsigned short*)((char*)d_ws + 1024);       // 2*RING*16*512 bf16

  // flags must be zero at every launch (ws is poisoned once, never re-poisoned)
  hipMemsetAsync(d_ws, 0, 1024, stream);

  gru2_kernel<<<dim3(2 * NWG_L), dim3(BLK), 0, stream>>>(
      x, Wih1, Whh1, bih1, bhh1, Wih2, Whh2, bih2, bhh2,
      (float*)d_out, flags, ring);
}

// Round 2
// 35503.433 us; speedup vs baseline: 1.0456x; 1.0456x over previous
//
#include <hip/hip_runtime.h>
#include <hip/hip_bf16.h>

// 2-layer GRU (torch gate order r,z,n) + residual, B=16 T=4096 IN=H=512.
// Persistent pipelined kernel: 32 WGs per layer, each owns 16 hidden units.
// Waves 0-2: input-side matvec (x for layer1, y-ring for layer2), gates r/z/n.
// Waves 3-5: hidden-side matvec, gates r/z/n. Weights stationary in VGPRs as
// bf16 MFMA B-fragments.
//
// Round-2 change: NO agent fences (buffer_inv/buffer_wbl2 per step was ~7us/step).
// Cross-XCD traffic (h/y rings, residual y, progress counters) uses per-access
// coherence: inline-asm global loads/stores with sc0 sc1 (bypass L1+L2, L3 is
// the coherence point). One monotonic counter per layer (atomicAdd, value
// 32*(steps done)) replaces 32 flags. x/weights/out stay normally cached.

namespace {

constexpr int BATCH = 16;
constexpr int SEQ   = 4096;
constexpr int HD    = 512;   // hidden == input dim
constexpr int NWG_L = 32;    // workgroups per layer
constexpr int SLICE = 16;    // hidden units per WG
constexpr int RING  = 8;     // ring slots per layer
constexpr int BLK   = 6 * 64;

typedef short bf16x8 __attribute__((ext_vector_type(8)));
typedef float f32x4  __attribute__((ext_vector_type(4)));

__device__ __forceinline__ unsigned short f2bf(float f) {
  unsigned u = __float_as_uint(f);
  return (unsigned short)((u + 0x7fffu + ((u >> 16) & 1u)) >> 16);  // RNE
}
__device__ __forceinline__ float bf2f(unsigned short s) {
  return __uint_as_float(((unsigned)s) << 16);
}

__device__ __forceinline__ void wait_cnt_ge(const unsigned* c, unsigned tgt) {
  while (__hip_atomic_load(c, __ATOMIC_RELAXED, __HIP_MEMORY_SCOPE_AGENT) < tgt) {}
}

// coherent (L1+L2-bypass) 16B load, NO wait — caller drains vmcnt once.
__device__ __forceinline__ void ld_frag_sc(bf16x8* dst, const unsigned short* p) {
  asm volatile("global_load_dwordx4 %0, %1, off sc0 sc1"
               : "=v"(*dst) : "v"(p) : "memory");
}

#define MFMA16(a, b, c) __builtin_amdgcn_mfma_f32_16x16x32_bf16((a), (b), (c), 0, 0, 0)

__global__ __launch_bounds__(BLK, 1) void gru2_kernel(
    const float* __restrict__ x,
    const float* __restrict__ Wih1, const float* __restrict__ Whh1,
    const float* __restrict__ bih1, const float* __restrict__ bhh1,
    const float* __restrict__ Wih2, const float* __restrict__ Whh2,
    const float* __restrict__ bih2, const float* __restrict__ bhh2,
    float* __restrict__ out,
    unsigned* cnt,              // [2] monotonic step counters (zeroed each launch)
    unsigned short* ring)       // [2][RING][BATCH][HD] bf16
{
  const int wg    = blockIdx.x;
  const int layer = wg >> 5;        // 0 or 1
  const int g     = wg & 31;        // slice id within layer
  const int tid   = threadIdx.x;
  const int w     = tid >> 6;       // wave 0..5
  const int lane  = tid & 63;
  const int nidx  = lane & 15;      // A-row (batch) / B-col (unit)
  const int kgrp  = lane >> 4;      // 0..3

  __shared__ float gate_buf[6][16][16];  // [wave][batch][unit] fp32 pre-acts
  __shared__ float h_own[16][16];        // own slice of h, fp32 (memory path)

  const float* Wih = layer ? Wih2 : Wih1;
  const float* Whh = layer ? Whh2 : Whh1;
  const float* bih = layer ? bih2 : bih1;
  const float* bhh = layer ? bhh2 : bhh1;

  unsigned* cnt1 = cnt;          // layer-1 progress (y producer)
  unsigned* cnt2 = cnt + 1;      // layer-2 progress
  unsigned* cnt_own = layer ? cnt2 : cnt1;

  const unsigned short* ring1 = ring;  // y ring
  unsigned short* ring_own = ring + (size_t)layer * (RING * BATCH * HD);

  if (tid < 256) h_own[tid >> 4][tid & 15] = 0.f;

  // ---- stationary weight fragments: wave w -> (input|hidden) x gate ----
  const int gate = (w < 3) ? w : (w - 3);
  const float* Wmat = (w < 3) ? Wih : Whh;
  const float* wrow = Wmat + ((size_t)gate * HD + (size_t)g * SLICE + nidx) * HD + kgrp * 8;
  bf16x8 bfrag[16];
  #pragma unroll
  for (int kk = 0; kk < 16; ++kk) {
    const float* p = wrow + kk * 32;
    bf16x8 f;
    #pragma unroll
    for (int i = 0; i < 8; ++i) f[i] = (short)f2bf(p[i]);
    bfrag[kk] = f;
  }

  float bi_r = 0, bi_z = 0, bi_n = 0, bh_r = 0, bh_z = 0, bh_n = 0;
  if (tid < 256) {
    int u = g * SLICE + (tid & 15);
    bi_r = bih[u]; bi_z = bih[HD + u]; bi_n = bih[2 * HD + u];
    bh_r = bhh[u]; bh_z = bhh[HD + u]; bh_n = bhh[2 * HD + u];
  }
  __syncthreads();

  for (int t = 0; t < SEQ; ++t) {
    f32x4 ac0 = {0.f,0.f,0.f,0.f}, ac1 = {0.f,0.f,0.f,0.f};
    f32x4 ac2 = {0.f,0.f,0.f,0.f}, ac3 = {0.f,0.f,0.f,0.f};

    if (w < 3) {
      if (layer == 0) {
        // ---------- layer-1 input matvec: x fp32, normally cached ----------
        const float* px = x + ((size_t)nidx * SEQ + t) * HD + kgrp * 8;
        #pragma unroll
        for (int kk = 0; kk < 16; ++kk) {
          const float* p = px + kk * 32;
          bf16x8 a;
          #pragma unroll
          for (int i = 0; i < 8; ++i) a[i] = (short)f2bf(p[i]);
          if ((kk & 3) == 0)      ac0 = MFMA16(a, bfrag[kk], ac0);
          else if ((kk & 3) == 1) ac1 = MFMA16(a, bfrag[kk], ac1);
          else if ((kk & 3) == 2) ac2 = MFMA16(a, bfrag[kk], ac2);
          else                    ac3 = MFMA16(a, bfrag[kk], ac3);
        }
        // back-pressure: don't let epilogue overwrite y ring slot t&7 before
        // all layer-2 WGs consumed y_{t-8} (their step t-8 complete).
        if (t >= RING) wait_cnt_ge(cnt2, 32u * (unsigned)(t - RING + 1));
      } else {
        // ---------- layer-2 input matvec: y_t from ring (coherent) ----------
        wait_cnt_ge(cnt1, 32u * (unsigned)(t + 1));
        const unsigned short* py =
            ring1 + ((size_t)(t & (RING - 1)) * BATCH + nidx) * HD + kgrp * 8;
        bf16x8 afr[16];
        #pragma unroll
        for (int kk = 0; kk < 16; ++kk) ld_frag_sc(&afr[kk], py + kk * 32);
        asm volatile("s_waitcnt vmcnt(0)" ::: "memory");
        __builtin_amdgcn_sched_barrier(0);
        #pragma unroll
        for (int kk = 0; kk < 16; ++kk) {
          if ((kk & 3) == 0)      ac0 = MFMA16(afr[kk], bfrag[kk], ac0);
          else if ((kk & 3) == 1) ac1 = MFMA16(afr[kk], bfrag[kk], ac1);
          else if ((kk & 3) == 2) ac2 = MFMA16(afr[kk], bfrag[kk], ac2);
          else                    ac3 = MFMA16(afr[kk], bfrag[kk], ac3);
        }
      }
    } else {
      // ---------- hidden matvec: h_{t-1} from own ring (coherent) ----------
      if (t > 0) {
        wait_cnt_ge(cnt_own, 32u * (unsigned)t);
        const unsigned short* ph =
            ring_own + ((size_t)((t - 1) & (RING - 1)) * BATCH + nidx) * HD + kgrp * 8;
        bf16x8 afr[16];
        #pragma unroll
        for (int kk = 0; kk < 16; ++kk) ld_frag_sc(&afr[kk], ph + kk * 32);
        asm volatile("s_waitcnt vmcnt(0)" ::: "memory");
        __builtin_amdgcn_sched_barrier(0);
        #pragma unroll
        for (int kk = 0; kk < 16; ++kk) {
          if ((kk & 3) == 0)      ac0 = MFMA16(afr[kk], bfrag[kk], ac0);
          else if ((kk & 3) == 1) ac1 = MFMA16(afr[kk], bfrag[kk], ac1);
          else if ((kk & 3) == 2) ac2 = MFMA16(afr[kk], bfrag[kk], ac2);
          else                    ac3 = MFMA16(afr[kk], bfrag[kk], ac3);
        }
      }
      // t == 0: h = 0 -> matvec contributes 0
    }

    f32x4 acc = (ac0 + ac1) + (ac2 + ac3);
    // C/D layout: col = lane&15 (unit), row = (lane>>4)*4 + j (batch)
    #pragma unroll
    for (int j = 0; j < 4; ++j) gate_buf[w][kgrp * 4 + j][nidx] = acc[j];
    __syncthreads();

    // ---------- epilogue: gates + state update + publish ----------
    if (tid < 256) {
      const int b = tid >> 4, u = tid & 15;
      // issue residual-y load early (coherent; layer-2, even-u lanes load pairs)
      unsigned ypk = 0;
      const unsigned short* pyr =
          ring1 + ((size_t)(t & (RING - 1)) * BATCH + b) * HD + g * SLICE + (u & ~1);
      if (layer == 1 && (u & 1) == 0) {
        asm volatile("global_load_dword %0, %1, off sc0 sc1"
                     : "=v"(ypk) : "v"(pyr) : "memory");
      }
      float rp = gate_buf[0][b][u] + bi_r + gate_buf[3][b][u] + bh_r;
      float zp = gate_buf[1][b][u] + bi_z + gate_buf[4][b][u] + bh_z;
      float xn = gate_buf[2][b][u] + bi_n;
      float hn = gate_buf[5][b][u] + bh_n;
      float r = 1.f / (1.f + __expf(-rp));
      float z = 1.f / (1.f + __expf(-zp));
      float n = tanhf(xn + r * hn);
      float hp = h_own[b][u];
      float hv = (1.f - z) * n + z * hp;
      h_own[b][u] = hv;
      // publish h (coherent, packed pairs from even lanes)
      unsigned hb = (unsigned)f2bf(hv);
      unsigned nb = (unsigned)__shfl_down((int)hb, 1);
      if ((u & 1) == 0) {
        unsigned pk = (hb & 0xffffu) | (nb << 16);
        unsigned short* pr =
            ring_own + ((size_t)(t & (RING - 1)) * BATCH + b) * HD + g * SLICE + u;
        asm volatile("global_store_dword %0, %1, off sc0 sc1"
                     :: "v"(pr), "v"(pk) : "memory");
      }
      // drain ring store (and y load) to the coherence point
      asm volatile("s_waitcnt vmcnt(0)" ::: "memory");
      __builtin_amdgcn_sched_barrier(0);
      if (layer == 1) {
        unsigned pk2 = (unsigned)__shfl((int)ypk, (lane & ~1));
        float y = bf2f((unsigned short)((u & 1) ? (pk2 >> 16) : (pk2 & 0xffffu)));
        out[((size_t)b * SEQ + t) * HD + g * SLICE + u] = hv + y;  // plain store
      }
    }
    __syncthreads();
    if (tid == 0) {
      // all ring stores of this WG are at the coherence point (vmcnt drained
      // before the barrier) -> relaxed add is a correct release.
      __hip_atomic_fetch_add(cnt_own, 1u, __ATOMIC_RELAXED, __HIP_MEMORY_SCOPE_AGENT);
    }
  }
}

}  // namespace

extern "C" void kernel_launch(void* const* d_in, const int* in_sizes, int n_in,
                              void* d_out, int out_size, void* d_ws, size_t ws_size,
                              hipStream_t stream) {
  const float* x    = (const float*)d_in[0];
  const float* Wih1 = (const float*)d_in[1];
  const float* Whh1 = (const float*)d_in[2];
  const float* bih1 = (const float*)d_in[3];
  const float* bhh1 = (const float*)d_in[4];
  const float* Wih2 = (const float*)d_in[5];
  const float* Whh2 = (const float*)d_in[6];
  const float* bih2 = (const float*)d_in[7];
  const float* bhh2 = (const float*)d_in[8];

  unsigned* cnt = (unsigned*)d_ws;                               // 2 u32
  unsigned short* ring = (unsigned short*)((char*)d_ws + 1024);  // 2*RING*16*512 bf16

  // counters must be zero at every launch (ws poisoned once, never re-poisoned)
  hipMemsetAsync(d_ws, 0, 1024, stream);

  gru2_kernel<<<dim3(2 * NWG_L), dim3(BLK), 0, stream>>>(
      x, Wih1, Whh1, bih1, bhh1, Wih2, Whh2, bih2, bhh2,
      (float*)d_out, cnt, ring);
}